// Round 15
// baseline (479.672 us; speedup 1.0000x reference)
//
#include <hip/hip_runtime.h>
#include <hip/hip_bf16.h>

#define D   1024
#define S   4096
#define NB  16
#define NH  16
#define NSC 16

using bf16x8 = __attribute__((ext_vector_type(8))) short;
using f32x4  = __attribute__((ext_vector_type(4))) float;

__device__ __forceinline__ short f2bf(float f) {
    unsigned int u = __float_as_uint(f);
    u += 0x7fffu + ((u >> 16) & 1u);   // RNE
    return (short)(u >> 16);
}
__device__ __forceinline__ unsigned int cvtpk(float a, float b) {
    unsigned int r;
    asm("v_cvt_pk_bf16_f32 %0, %1, %2" : "=v"(r) : "v"(a), "v"(b));
    return r;   // lo16 = bf16(a), hi16 = bf16(b), RNE
}
__device__ __forceinline__ float elu1(float x) {
    return x > 0.f ? x + 1.f : __expf(x);   // elu(x)+1
}

// ---------------- fused small prep: phiq (blocks 0..255) | wkt (blocks 256..1279) ----------------
__global__ __launch_bounds__(256) void prep2_kernel(
        const float* __restrict__ x, const float* __restrict__ Wq,
        const float* __restrict__ bq, float* __restrict__ phiq,
        const float* __restrict__ Wk, unsigned short* __restrict__ WkT)
{
    const int bid = blockIdx.x;
    const int t   = threadIdx.x;
    __shared__ float xl[D];
    __shared__ float tile[32][33];

    if (bid < 256) {
        // ---- phiq: o-chunk (bid&15)*64? No: keep R12 mapping: 4 o-chunks x 16 b => 64 blocks.
        // Use 256 blocks: b = bid>>4, o = (bid&15)*64 .. +63 handled by 256 threads? Keep it
        // simple and byte-equivalent to R12's phiq: b = bid>>4, o0 = (bid&15)*64, but R12 used
        // 256-thread o-chunks. Recast: o = o0 + (t&63), 4 j-quarters reduced via LDS.
        const int b  = bid >> 4;
        const int o0 = (bid & 15) * 64;
        const int ol = t & 63, jq = t >> 6;
        __shared__ float rnum[256];
        for (int i = t; i < D; i += 256) xl[i] = x[b * D + i];
        __syncthreads();
        float acc = 0.f;
        const int o = o0 + ol;
        for (int j = jq * 256; j < jq * 256 + 256; ++j)
            acc = fmaf(xl[j], Wq[(size_t)j * D + o], acc);
        rnum[t] = acc;
        __syncthreads();
        if (t < 64) {
            float s = rnum[t] + rnum[64 + t] + rnum[128 + t] + rnum[192 + t];
            phiq[b * D + o0 + t] = elu1(s + bq[o0 + t]);
        }
    } else {
        // ---- wkt: WkT[o][j] = bf16(Wk[j][o]), 32x32 tiles ----
        const int b3 = bid - 256;
        const int j0 = (b3 >> 5) * 32, o0 = (b3 & 31) * 32;
        const int tx = t & 31, ty = t >> 5;
#pragma unroll
        for (int r = 0; r < 4; ++r)
            tile[ty + r * 8][tx] = Wk[(size_t)(j0 + ty + r * 8) * D + o0 + tx];
        __syncthreads();
#pragma unroll
        for (int r = 0; r < 4; ++r) {
            const int o = o0 + ty + r * 8;
            WkT[(size_t)o * D + j0 + tx] = (unsigned short)f2bf(tile[tx][ty + r * 8]);
        }
    }
}

// ---------------- fused K-projection + phi + phi_q reduction -> w[b,h,s] ----------------
// R12-proven: 128x256 tile, BK=64, 4 waves 2x2. A staged f32 via global_load_lds
// (involution cs^(row&15)); B bf16 (involution cs^(row&7)); f32->bf16 at fragment-load
// via v_cvt_pk_bf16_f32. LDS 64 KB -> 2 blocks/CU. XCD-chunked grid, nt innermost.
__global__ __launch_bounds__(256, 2) void kgemm_kernel(
        const float* __restrict__ y, const unsigned short* __restrict__ WkT,
        const float* __restrict__ phiq, const float* __restrict__ bk,
        float* __restrict__ wbuf)
{
    const int bid = blockIdx.x;
    const int wg  = (bid & 7) * 256 + (bid >> 3);
    const int mt  = wg >> 2;           // 0..511
    const int nt  = wg & 3;            // 0..3
    const int b   = mt >> 5;
    const int s0  = (mt & 31) << 7;
    const int n0  = nt << 8;           // 256-col panel
    const int t   = threadIdx.x;
    const int wv  = t >> 6;
    const int l   = t & 63;
    const int wr  = wv >> 1, wc = wv & 1;
    const int l15 = l & 15, l16 = l >> 4;

    __shared__ float Af[128 * 64];   // 32 KB f32 A-tile, 16 slots/row (16B each)
    __shared__ short Bl[256 * 64];   // 32 KB bf16 B-tile, 8 slots/row

    f32x4 acc[4][8] = {};

    const float* yb = y + (size_t)(b * S + s0) * D;

    for (int kt = 0; kt < D / 64; ++kt) {
        const int k0 = kt * 64;
        // stage A (f32): 2048 slots of 16B (4 f32); involution cs^(row&15)
#pragma unroll
        for (int i = 0; i < 8; ++i) {
            const int slot0 = i * 256 + wv * 64;   // wave-uniform base
            const int slot  = slot0 + l;
            const int row   = slot >> 4;           // 0..127
            const int cs    = slot & 15;
            const int ke    = (cs ^ (row & 15)) << 2;
            __builtin_amdgcn_global_load_lds(
                (const __attribute__((address_space(1))) unsigned int*)(yb + (size_t)row * D + k0 + ke),
                (__attribute__((address_space(3))) unsigned int*)(&Af[slot0 * 4]),
                16, 0, 0);
        }
        // stage B (bf16): 2048 slots; involution cs^(row&7)
#pragma unroll
        for (int i = 0; i < 8; ++i) {
            const int slot0 = i * 256 + wv * 64;
            const int slot  = slot0 + l;
            const int nrow  = slot >> 3;
            const int ke    = ((slot & 7) ^ (nrow & 7)) << 3;
            __builtin_amdgcn_global_load_lds(
                (const __attribute__((address_space(1))) unsigned int*)(WkT + (size_t)(n0 + nrow) * D + k0 + ke),
                (__attribute__((address_space(3))) unsigned int*)(&Bl[slot0 * 8]),
                16, 0, 0);
        }
        __syncthreads();
#pragma unroll
        for (int kk = 0; kk < 2; ++kk) {
            bf16x8 af[4], bfr[8];
            const int ksA = kk * 8 + l16 * 2;      // f32 slot pair base (slots of 4 f32)
            const int ksB = (kk << 2) + l16;       // bf16 slot
#pragma unroll
            for (int m = 0; m < 4; ++m) {
                const int row = wr * 64 + m * 16 + l15;
                const f32x4 lo = *reinterpret_cast<const f32x4*>(
                    &Af[row * 64 + ((ksA ^ (row & 15)) << 2)]);
                const f32x4 hi = *reinterpret_cast<const f32x4*>(
                    &Af[row * 64 + (((ksA + 1) ^ (row & 15)) << 2)]);
                union { unsigned int u[4]; bf16x8 v; } cv;
                cv.u[0] = cvtpk(lo[0], lo[1]);
                cv.u[1] = cvtpk(lo[2], lo[3]);
                cv.u[2] = cvtpk(hi[0], hi[1]);
                cv.u[3] = cvtpk(hi[2], hi[3]);
                af[m] = cv.v;
            }
#pragma unroll
            for (int n = 0; n < 8; ++n) {
                const int row = wc * 128 + n * 16 + l15;
                bfr[n] = *reinterpret_cast<const bf16x8*>(&Bl[row * 64 + ((ksB ^ (row & 7)) << 3)]);
            }
#pragma unroll
            for (int m = 0; m < 4; ++m)
#pragma unroll
                for (int n = 0; n < 8; ++n)
                    acc[m][n] = __builtin_amdgcn_mfma_f32_16x16x32_bf16(af[m], bfr[n], acc[m][n], 0, 0, 0);
        }
        __syncthreads();
    }

    // epilogue: wave covers 2 heads (cols n0+wc*128 .. +127)
    const int h0 = (n0 >> 6) + wc * 2;
    float pq[8], bkv[8];
#pragma unroll
    for (int n = 0; n < 8; ++n) {
        const int col = n0 + wc * 128 + n * 16 + l15;
        pq[n]  = phiq[b * D + col];
        bkv[n] = bk[col];
    }
#pragma unroll
    for (int m = 0; m < 4; ++m) {
#pragma unroll
        for (int j = 0; j < 4; ++j) {
            float rs0 = 0.f, rs1 = 0.f;
#pragma unroll
            for (int n = 0; n < 4; ++n) {
                rs0 += elu1(acc[m][n][j] + bkv[n]) * pq[n];
                rs1 += elu1(acc[m][n + 4][j] + bkv[n + 4]) * pq[n + 4];
            }
            rs0 += __shfl_xor(rs0, 1); rs1 += __shfl_xor(rs1, 1);
            rs0 += __shfl_xor(rs0, 2); rs1 += __shfl_xor(rs1, 2);
            rs0 += __shfl_xor(rs0, 4); rs1 += __shfl_xor(rs1, 4);
            rs0 += __shfl_xor(rs0, 8); rs1 += __shfl_xor(rs1, 8);
            if (l15 == 0) {
                const int row = s0 + wr * 64 + m * 16 + l16 * 4 + j;
                wbuf[(size_t)(b * NH + h0) * S + row]     = rs0;
                wbuf[(size_t)(b * NH + h0 + 1) * S + row] = rs1;
            }
        }
    }
}

// ---------------- t_part[sc][b][h][j] = sum_{s in chunk} w[b,h,s] * y[b,s,j] (f32) ----------------
__global__ __launch_bounds__(256) void tpart_kernel(
        const float* __restrict__ y, const float* __restrict__ wbuf,
        float* __restrict__ tpart)
{
    const int sc = blockIdx.x;   // 0..15 (256 s each)
    const int b  = blockIdx.y;
    const int t  = threadIdx.x;
    const int s0 = sc * 256;
    __shared__ float wl[16 * 256];
#pragma unroll
    for (int r = 0; r < 16; ++r) {
        const int lin = r * 256 + t;
        wl[lin] = wbuf[(size_t)(b * NH + (lin >> 8)) * S + s0 + (lin & 255)];
    }
    __syncthreads();
    float acc[16][4] = {};
    const float* yb = y + (size_t)(b * S + s0) * D + t * 4;
    for (int si = 0; si < 256; ++si) {
        const float4 v = *reinterpret_cast<const float4*>(yb + (size_t)si * D);
#pragma unroll
        for (int hh = 0; hh < 16; ++hh) {
            const float wv = wl[hh * 256 + si];
            acc[hh][0] = fmaf(wv, v.x, acc[hh][0]);
            acc[hh][1] = fmaf(wv, v.y, acc[hh][1]);
            acc[hh][2] = fmaf(wv, v.z, acc[hh][2]);
            acc[hh][3] = fmaf(wv, v.w, acc[hh][3]);
        }
    }
    float* tp = tpart + ((size_t)(sc * NB + b) * NH) * D + t * 4;
#pragma unroll
    for (int hh = 0; hh < 16; ++hh) {
        float4 o;
        o.x = acc[hh][0]; o.y = acc[hh][1]; o.z = acc[hh][2]; o.w = acc[hh][3];
        *reinterpret_cast<float4*>(tp + hh * D) = o;
    }
}

// ---------------- ctx: absorbs tred (strip-sum of tpart) + denom + t@Wv ----------------
__global__ __launch_bounds__(256) void ctx_kernel(
        const float* __restrict__ wbuf, const float* __restrict__ tpart,
        const float* __restrict__ Wv, const float* __restrict__ bv,
        float* __restrict__ ctx)
{
    const int b = blockIdx.x >> 4, h = blockIdx.x & 15;
    const int t = threadIdx.x;
    __shared__ float t_l[D];
    __shared__ float rnum[256];
    __shared__ float rden[4];
    // denom = sum_s w
    const float* wr_ = wbuf + (size_t)(b * NH + h) * S;
    float dp = 0.f;
    for (int i = t; i < S; i += 256) dp += wr_[i];
#pragma unroll
    for (int off = 1; off < 64; off <<= 1) dp += __shfl_xor(dp, off);
    if ((t & 63) == 0) rden[t >> 6] = dp;
    // t = strip-sum of tpart (absorbed tred)
    float4 a = {0.f, 0.f, 0.f, 0.f};
    for (int sc = 0; sc < NSC; ++sc) {
        const float4 v = *reinterpret_cast<const float4*>(
            tpart + ((size_t)((sc * NB + b) * NH + h)) * D + t * 4);
        a.x += v.x; a.y += v.y; a.z += v.z; a.w += v.w;
    }
    *reinterpret_cast<float4*>(&t_l[t * 4]) = a;
    __syncthreads();
    const float denom = rden[0] + rden[1] + rden[2] + rden[3];
    const int v = t & 63, jq = t >> 6;
    float np = 0.f;
    for (int j = jq * 256; j < jq * 256 + 256; ++j)
        np = fmaf(t_l[j], Wv[(size_t)j * D + h * 64 + v], np);
    rnum[t] = np;
    __syncthreads();
    if (t < 64) {
        float num = rnum[t] + rnum[64 + t] + rnum[128 + t] + rnum[192 + t];
        num += denom * bv[h * 64 + t];
        ctx[(size_t)b * D + h * 64 + t] = num / (denom + 1e-6f);
    }
}

// ---------------- out = ctx @ Wo + bo ----------------
__global__ __launch_bounds__(256) void out_kernel(
        const float* __restrict__ ctx, const float* __restrict__ Wo,
        const float* __restrict__ bo, float* __restrict__ out)
{
    const int b = blockIdx.y;
    const int o = blockIdx.x * 256 + threadIdx.x;
    __shared__ float cl[D];
    for (int i = threadIdx.x; i < D; i += 256) cl[i] = ctx[(size_t)b * D + i];
    __syncthreads();
    float acc = bo[o];
    for (int j = 0; j < D; ++j) acc = fmaf(cl[j], Wo[(size_t)j * D + o], acc);
    out[(size_t)b * D + o] = acc;
}

extern "C" void kernel_launch(void* const* d_in, const int* in_sizes, int n_in,
                              void* d_out, int out_size, void* d_ws, size_t ws_size,
                              hipStream_t stream) {
    const float* y  = (const float*)d_in[0];
    const float* x  = (const float*)d_in[1];
    const float* Wq = (const float*)d_in[2];
    const float* bq = (const float*)d_in[3];
    const float* Wk = (const float*)d_in[4];
    const float* bk = (const float*)d_in[5];
    const float* Wv = (const float*)d_in[6];
    const float* bv = (const float*)d_in[7];
    const float* Wo = (const float*)d_in[8];
    const float* bo = (const float*)d_in[9];
    float* out = (float*)d_out;

    char* ws = (char*)d_ws;
    size_t off = 0;
    unsigned short* WkT  = (unsigned short*)(ws + off); off += (size_t)D * D * 2;             // 2 MB
    float*          phiq = (float*)(ws + off);          off += (size_t)NB * D * 4;            // 64 KB
    float*          wbuf = (float*)(ws + off);          off += (size_t)NB * NH * S * 4;       // 4 MB
    float*          tpart= (float*)(ws + off);          off += (size_t)NSC * NB * NH * D * 4; // 16 MB
    float*          ctx  = (float*)(ws + off);          off += (size_t)NB * D * 4;            // 64 KB

    prep2_kernel<<<1280, 256, 0, stream>>>(x, Wq, bq, phiq, Wk, WkT);
    kgemm_kernel<<<2048, 256, 0, stream>>>(y, WkT, phiq, bk, wbuf);
    tpart_kernel<<<dim3(NSC, NB), 256, 0, stream>>>(y, wbuf, tpart);
    ctx_kernel  <<<256, 256, 0, stream>>>(wbuf, tpart, Wv, bv, ctx);
    out_kernel  <<<dim3(4, NB), 256, 0, stream>>>(ctx, Wo, bo, out);
}

// Round 16
// 325.741 us; speedup vs baseline: 1.4726x; 1.4726x over previous
//
#include <hip/hip_runtime.h>
#include <hip/hip_bf16.h>

#define D   1024
#define S   4096
#define NB  16
#define NH  16
#define NSC 32   // tpart strips of 128 rows -> 512 blocks (2/CU) for HBM saturation

using bf16x8 = __attribute__((ext_vector_type(8))) short;
using f32x4  = __attribute__((ext_vector_type(4))) float;

__device__ __forceinline__ short f2bf(float f) {
    unsigned int u = __float_as_uint(f);
    u += 0x7fffu + ((u >> 16) & 1u);   // RNE
    return (short)(u >> 16);
}
__device__ __forceinline__ unsigned int cvtpk(float a, float b) {
    unsigned int r;
    asm("v_cvt_pk_bf16_f32 %0, %1, %2" : "=v"(r) : "v"(a), "v"(b));
    return r;   // lo16 = bf16(a), hi16 = bf16(b), RNE
}
__device__ __forceinline__ float elu1(float x) {
    return x > 0.f ? x + 1.f : __expf(x);   // elu(x)+1
}

// ---------------- phi_q = elu(x @ Wq + bq) + 1 : [16,1024] ----------------
__global__ __launch_bounds__(256) void phiq_kernel(const float* __restrict__ x,
        const float* __restrict__ Wq, const float* __restrict__ bq,
        float* __restrict__ phiq)
{
    const int b = blockIdx.y;
    const int o = blockIdx.x * 256 + threadIdx.x;
    __shared__ float xl[D];
    for (int i = threadIdx.x; i < D; i += 256) xl[i] = x[b * D + i];
    __syncthreads();
    float acc = bq[o];
    for (int j = 0; j < D; ++j) acc = fmaf(xl[j], Wq[(size_t)j * D + o], acc);
    phiq[b * D + o] = elu1(acc);
}

// ---------------- WkT[o][j] = bf16(Wk[j][o]) ----------------
__global__ __launch_bounds__(256) void wkt_kernel(const float* __restrict__ Wk,
        unsigned short* __restrict__ WkT)
{
    __shared__ float tile[32][33];
    const int tx = threadIdx.x & 31, ty = threadIdx.x >> 5;
    const int j0 = blockIdx.y * 32, o0 = blockIdx.x * 32;
#pragma unroll
    for (int r = 0; r < 4; ++r)
        tile[ty + r * 8][tx] = Wk[(size_t)(j0 + ty + r * 8) * D + o0 + tx];
    __syncthreads();
#pragma unroll
    for (int r = 0; r < 4; ++r) {
        const int o = o0 + ty + r * 8;
        WkT[(size_t)o * D + j0 + tx] = (unsigned short)f2bf(tile[tx][ty + r * 8]);
    }
}

// ---------------- fused K-projection + phi + phi_q reduction -> w[b,h,s] ----------------
// R12-proven: 128x256 tile, BK=64, 4 waves 2x2. A staged f32 via global_load_lds
// (involution cs^(row&15)); B bf16 (involution cs^(row&7)); f32->bf16 at fragment-load
// via v_cvt_pk_bf16_f32. LDS 64 KB -> 2 blocks/CU. XCD-chunked grid, nt innermost.
__global__ __launch_bounds__(256, 2) void kgemm_kernel(
        const float* __restrict__ y, const unsigned short* __restrict__ WkT,
        const float* __restrict__ phiq, const float* __restrict__ bk,
        float* __restrict__ wbuf)
{
    const int bid = blockIdx.x;
    const int wg  = (bid & 7) * 256 + (bid >> 3);
    const int mt  = wg >> 2;           // 0..511
    const int nt  = wg & 3;            // 0..3
    const int b   = mt >> 5;
    const int s0  = (mt & 31) << 7;
    const int n0  = nt << 8;           // 256-col panel
    const int t   = threadIdx.x;
    const int wv  = t >> 6;
    const int l   = t & 63;
    const int wr  = wv >> 1, wc = wv & 1;
    const int l15 = l & 15, l16 = l >> 4;

    __shared__ float Af[128 * 64];   // 32 KB f32 A-tile, 16 slots/row (16B each)
    __shared__ short Bl[256 * 64];   // 32 KB bf16 B-tile, 8 slots/row

    f32x4 acc[4][8] = {};

    const float* yb = y + (size_t)(b * S + s0) * D;

    for (int kt = 0; kt < D / 64; ++kt) {
        const int k0 = kt * 64;
        // stage A (f32): 2048 slots of 16B (4 f32); involution cs^(row&15)
#pragma unroll
        for (int i = 0; i < 8; ++i) {
            const int slot0 = i * 256 + wv * 64;   // wave-uniform base
            const int slot  = slot0 + l;
            const int row   = slot >> 4;           // 0..127
            const int cs    = slot & 15;
            const int ke    = (cs ^ (row & 15)) << 2;
            __builtin_amdgcn_global_load_lds(
                (const __attribute__((address_space(1))) unsigned int*)(yb + (size_t)row * D + k0 + ke),
                (__attribute__((address_space(3))) unsigned int*)(&Af[slot0 * 4]),
                16, 0, 0);
        }
        // stage B (bf16): 2048 slots; involution cs^(row&7)
#pragma unroll
        for (int i = 0; i < 8; ++i) {
            const int slot0 = i * 256 + wv * 64;
            const int slot  = slot0 + l;
            const int nrow  = slot >> 3;
            const int ke    = ((slot & 7) ^ (nrow & 7)) << 3;
            __builtin_amdgcn_global_load_lds(
                (const __attribute__((address_space(1))) unsigned int*)(WkT + (size_t)(n0 + nrow) * D + k0 + ke),
                (__attribute__((address_space(3))) unsigned int*)(&Bl[slot0 * 8]),
                16, 0, 0);
        }
        __syncthreads();
#pragma unroll
        for (int kk = 0; kk < 2; ++kk) {
            bf16x8 af[4], bfr[8];
            const int ksA = kk * 8 + l16 * 2;      // f32 slot pair base (slots of 4 f32)
            const int ksB = (kk << 2) + l16;       // bf16 slot
#pragma unroll
            for (int m = 0; m < 4; ++m) {
                const int row = wr * 64 + m * 16 + l15;
                const f32x4 lo = *reinterpret_cast<const f32x4*>(
                    &Af[row * 64 + ((ksA ^ (row & 15)) << 2)]);
                const f32x4 hi = *reinterpret_cast<const f32x4*>(
                    &Af[row * 64 + (((ksA + 1) ^ (row & 15)) << 2)]);
                union { unsigned int u[4]; bf16x8 v; } cv;
                cv.u[0] = cvtpk(lo[0], lo[1]);
                cv.u[1] = cvtpk(lo[2], lo[3]);
                cv.u[2] = cvtpk(hi[0], hi[1]);
                cv.u[3] = cvtpk(hi[2], hi[3]);
                af[m] = cv.v;
            }
#pragma unroll
            for (int n = 0; n < 8; ++n) {
                const int row = wc * 128 + n * 16 + l15;
                bfr[n] = *reinterpret_cast<const bf16x8*>(&Bl[row * 64 + ((ksB ^ (row & 7)) << 3)]);
            }
#pragma unroll
            for (int m = 0; m < 4; ++m)
#pragma unroll
                for (int n = 0; n < 8; ++n)
                    acc[m][n] = __builtin_amdgcn_mfma_f32_16x16x32_bf16(af[m], bfr[n], acc[m][n], 0, 0, 0);
        }
        __syncthreads();
    }

    // epilogue: wave covers 2 heads (cols n0+wc*128 .. +127)
    const int h0 = (n0 >> 6) + wc * 2;
    float pq[8], bkv[8];
#pragma unroll
    for (int n = 0; n < 8; ++n) {
        const int col = n0 + wc * 128 + n * 16 + l15;
        pq[n]  = phiq[b * D + col];
        bkv[n] = bk[col];
    }
#pragma unroll
    for (int m = 0; m < 4; ++m) {
#pragma unroll
        for (int j = 0; j < 4; ++j) {
            float rs0 = 0.f, rs1 = 0.f;
#pragma unroll
            for (int n = 0; n < 4; ++n) {
                rs0 += elu1(acc[m][n][j] + bkv[n]) * pq[n];
                rs1 += elu1(acc[m][n + 4][j] + bkv[n + 4]) * pq[n + 4];
            }
            rs0 += __shfl_xor(rs0, 1); rs1 += __shfl_xor(rs1, 1);
            rs0 += __shfl_xor(rs0, 2); rs1 += __shfl_xor(rs1, 2);
            rs0 += __shfl_xor(rs0, 4); rs1 += __shfl_xor(rs1, 4);
            rs0 += __shfl_xor(rs0, 8); rs1 += __shfl_xor(rs1, 8);
            if (l15 == 0) {
                const int row = s0 + wr * 64 + m * 16 + l16 * 4 + j;
                wbuf[(size_t)(b * NH + h0) * S + row]     = rs0;
                wbuf[(size_t)(b * NH + h0 + 1) * S + row] = rs1;
            }
        }
    }
}

// ---------------- t_part[sc][b][h][j] = sum_{s in strip of 128} w[b,h,s] * y[b,s,j] ----------------
__global__ __launch_bounds__(256) void tpart_kernel(
        const float* __restrict__ y, const float* __restrict__ wbuf,
        float* __restrict__ tpart)
{
    const int sc = blockIdx.x;   // 0..31 (128 s each)
    const int b  = blockIdx.y;
    const int t  = threadIdx.x;
    const int s0 = sc * 128;
    __shared__ float wl[16 * 128];
#pragma unroll
    for (int r = 0; r < 8; ++r) {
        const int lin = r * 256 + t;
        wl[lin] = wbuf[(size_t)(b * NH + (lin >> 7)) * S + s0 + (lin & 127)];
    }
    __syncthreads();
    float acc[16][4] = {};
    const float* yb = y + (size_t)(b * S + s0) * D + t * 4;
    for (int si = 0; si < 128; ++si) {
        const float4 v = *reinterpret_cast<const float4*>(yb + (size_t)si * D);
#pragma unroll
        for (int hh = 0; hh < 16; ++hh) {
            const float wv = wl[hh * 128 + si];
            acc[hh][0] = fmaf(wv, v.x, acc[hh][0]);
            acc[hh][1] = fmaf(wv, v.y, acc[hh][1]);
            acc[hh][2] = fmaf(wv, v.z, acc[hh][2]);
            acc[hh][3] = fmaf(wv, v.w, acc[hh][3]);
        }
    }
    float* tp = tpart + ((size_t)(sc * NB + b) * NH) * D + t * 4;
#pragma unroll
    for (int hh = 0; hh < 16; ++hh) {
        float4 o;
        o.x = acc[hh][0]; o.y = acc[hh][1]; o.z = acc[hh][2]; o.w = acc[hh][3];
        *reinterpret_cast<float4*>(tp + hh * D) = o;
    }
}

__global__ __launch_bounds__(256) void tred_kernel(const float* __restrict__ tpart,
        float* __restrict__ tbuf)
{
    const int idx = blockIdx.x * 256 + threadIdx.x;   // 0..262143
    float s = 0.f;
#pragma unroll
    for (int sc = 0; sc < NSC; ++sc) s += tpart[(size_t)sc * (NB * NH * D) + idx];
    tbuf[idx] = s;
}

// ---------------- ctx[b, h*64+v] = (t[b,h,:]@Wv[:,h*64+v] + denom*bv) / (denom+eps) ----------------
__global__ __launch_bounds__(256) void ctx_kernel(
        const float* __restrict__ wbuf, const float* __restrict__ tbuf,
        const float* __restrict__ Wv, const float* __restrict__ bv,
        float* __restrict__ ctx)
{
    const int b = blockIdx.x >> 4, h = blockIdx.x & 15;
    const int t = threadIdx.x;
    const int v = t & 63, jq = t >> 6;
    __shared__ float rnum[256];
    __shared__ float rden[4];
    const float* wr_ = wbuf + (size_t)(b * NH + h) * S;
    float dp = 0.f;
    for (int i = t; i < S; i += 256) dp += wr_[i];
#pragma unroll
    for (int off = 1; off < 64; off <<= 1) dp += __shfl_xor(dp, off);
    if ((t & 63) == 0) rden[t >> 6] = dp;
    const float* tr = tbuf + (size_t)(b * NH + h) * D;
    float np = 0.f;
    for (int j = jq * 256; j < jq * 256 + 256; ++j)
        np = fmaf(tr[j], Wv[(size_t)j * D + h * 64 + v], np);
    rnum[t] = np;
    __syncthreads();
    if (t < 64) {
        const float denom = rden[0] + rden[1] + rden[2] + rden[3];
        float num = rnum[v] + rnum[64 + v] + rnum[128 + v] + rnum[192 + v];
        num += denom * bv[h * 64 + v];
        ctx[(size_t)b * D + h * 64 + v] = num / (denom + 1e-6f);
    }
}

// ---------------- out = ctx @ Wo + bo ----------------
__global__ __launch_bounds__(256) void out_kernel(
        const float* __restrict__ ctx, const float* __restrict__ Wo,
        const float* __restrict__ bo, float* __restrict__ out)
{
    const int b = blockIdx.y;
    const int o = blockIdx.x * 256 + threadIdx.x;
    __shared__ float cl[D];
    for (int i = threadIdx.x; i < D; i += 256) cl[i] = ctx[(size_t)b * D + i];
    __syncthreads();
    float acc = bo[o];
    for (int j = 0; j < D; ++j) acc = fmaf(cl[j], Wo[(size_t)j * D + o], acc);
    out[(size_t)b * D + o] = acc;
}

extern "C" void kernel_launch(void* const* d_in, const int* in_sizes, int n_in,
                              void* d_out, int out_size, void* d_ws, size_t ws_size,
                              hipStream_t stream) {
    const float* y  = (const float*)d_in[0];
    const float* x  = (const float*)d_in[1];
    const float* Wq = (const float*)d_in[2];
    const float* bq = (const float*)d_in[3];
    const float* Wk = (const float*)d_in[4];
    const float* bk = (const float*)d_in[5];
    const float* Wv = (const float*)d_in[6];
    const float* bv = (const float*)d_in[7];
    const float* Wo = (const float*)d_in[8];
    const float* bo = (const float*)d_in[9];
    float* out = (float*)d_out;

    char* ws = (char*)d_ws;
    size_t off = 0;
    unsigned short* WkT  = (unsigned short*)(ws + off); off += (size_t)D * D * 2;             // 2 MB
    float*          phiq = (float*)(ws + off);          off += (size_t)NB * D * 4;            // 64 KB
    float*          wbuf = (float*)(ws + off);          off += (size_t)NB * NH * S * 4;       // 4 MB
    float*          tpart= (float*)(ws + off);          off += (size_t)NSC * NB * NH * D * 4; // 32 MB
    float*          tbuf = (float*)(ws + off);          off += (size_t)NB * NH * D * 4;       // 1 MB
    float*          ctx  = (float*)(ws + off);          off += (size_t)NB * D * 4;            // 64 KB

    phiq_kernel<<<dim3(4, NB), 256, 0, stream>>>(x, Wq, bq, phiq);
    wkt_kernel <<<dim3(32, 32), 256, 0, stream>>>(Wk, WkT);
    kgemm_kernel<<<2048, 256, 0, stream>>>(y, WkT, phiq, bk, wbuf);
    tpart_kernel<<<dim3(NSC, NB), 256, 0, stream>>>(y, wbuf, tpart);
    tred_kernel <<<1024, 256, 0, stream>>>(tpart, tbuf);
    ctx_kernel  <<<256, 256, 0, stream>>>(wbuf, tbuf, Wv, bv, ctx);
    out_kernel  <<<dim3(4, NB), 256, 0, stream>>>(ctx, Wo, bo, out);
}